// Round 5
// baseline (653.517 us; speedup 1.0000x reference)
//
#include <hip/hip_runtime.h>
#include <hip/hip_bf16.h>

typedef unsigned short u16;
typedef __attribute__((ext_vector_type(4))) unsigned short u16x4;
typedef __attribute__((ext_vector_type(8))) unsigned short u16x8;
typedef __attribute__((ext_vector_type(8))) short s16x8;
typedef __attribute__((ext_vector_type(4))) float f32x4;

#define HEADS 12
#define NSEQ 1024
#define DIMM 768
#define DHEAD 64

__device__ __forceinline__ float b2f(u16 h) {
  union { unsigned u; float f; } v; v.u = ((unsigned)h) << 16; return v.f;
}
__device__ __forceinline__ u16 f2b(float f) {
  union { float f; unsigned u; } v; v.f = f;
  unsigned r = v.u + 0x7fffu + ((v.u >> 16) & 1u);
  return (u16)(r >> 16);
}
__device__ __forceinline__ float ld(const void* p, long i, bool f32m) {
  return f32m ? ((const float*)p)[i] : b2f(((const u16*)p)[i]);
}

// probe lnq_g (all ones): f32 word = 0x3F800000, bf16-pair word = 0x3F803F80
__global__ void detect_dtype(const unsigned* __restrict__ probe, int* __restrict__ flag)
{
  if (threadIdx.x == 0) { flag[0] = (probe[0] == 0x3F800000u) ? 1 : 0; flag[1] = 0; }
}

// ---------------------------------------------------------------- GEMM (BT)
// C[m][n] = alpha * sum_k A[m][k] * BT[n][k] (+bias) (GELU) (+resid); C bf16.
template<int BM, int BN, bool GELU, bool RESID>
__global__ __launch_bounds__(256)
void gemm_bt(const u16* __restrict__ A, const u16* __restrict__ BT,
             const void* __restrict__ bias, const u16* __restrict__ resid,
             u16* __restrict__ C, const int* __restrict__ fl,
             int K, int lda, int ldb, int ldc,
             long sAo, long sAi, long sBo, long sBi, long sCo, long sCi,
             float alpha)
{
  constexpr int BK = 32;
  constexpr int PAD = 8;
  constexpr int WM = BM / 2, WN = BN / 2;
  constexpr int MI = WM / 16, NI = WN / 16;
  __shared__ u16 As[BM][BK + PAD];
  __shared__ u16 Bs[BN][BK + PAD];

  const int z = blockIdx.z;
  const int zo = z / HEADS, zi = z - zo * HEADS;
  const u16* Ab = A + zo * sAo + zi * sAi;
  const u16* Bb = BT + zo * sBo + zi * sBi;
  u16* Cb = C + zo * sCo + zi * sCi;

  const int m0 = blockIdx.x * BM;
  const int n0 = blockIdx.y * BN;
  const int tid = threadIdx.x;
  const int lane = tid & 63;
  const int wv = tid >> 6;
  const int wm0 = (wv >> 1) * WM;
  const int wn0 = (wv & 1) * WN;
  const int l15 = lane & 15;
  const int quad = lane >> 4;

  f32x4 acc[MI][NI];
  #pragma unroll
  for (int i = 0; i < MI; ++i)
    #pragma unroll
    for (int j = 0; j < NI; ++j)
      acc[i][j] = {0.f, 0.f, 0.f, 0.f};

  const int r = tid >> 2;
  const int c8 = (tid & 3) * 8;

  for (int k0 = 0; k0 < K; k0 += BK) {
    __syncthreads();
    #pragma unroll
    for (int rr = 0; rr < BM; rr += 64)
      *(u16x8*)&As[r + rr][c8] = *(const u16x8*)&Ab[(long)(m0 + r + rr) * lda + k0 + c8];
    #pragma unroll
    for (int rr = 0; rr < BN; rr += 64)
      *(u16x8*)&Bs[r + rr][c8] = *(const u16x8*)&Bb[(long)(n0 + r + rr) * ldb + k0 + c8];
    __syncthreads();

    s16x8 af[MI], bfr[NI];
    #pragma unroll
    for (int i = 0; i < MI; ++i)
      af[i] = *(const s16x8*)&As[wm0 + i * 16 + l15][quad * 8];
    #pragma unroll
    for (int j = 0; j < NI; ++j)
      bfr[j] = *(const s16x8*)&Bs[wn0 + j * 16 + l15][quad * 8];
    #pragma unroll
    for (int i = 0; i < MI; ++i)
      #pragma unroll
      for (int j = 0; j < NI; ++j)
        acc[i][j] = __builtin_amdgcn_mfma_f32_16x16x32_bf16(af[i], bfr[j], acc[i][j], 0, 0, 0);
  }

  const bool f32m = *fl != 0;
  #pragma unroll
  for (int i = 0; i < MI; ++i) {
    #pragma unroll
    for (int j = 0; j < NI; ++j) {
      const int col = n0 + wn0 + j * 16 + l15;
      const float bvv = bias ? ld(bias, col, f32m) : 0.f;
      #pragma unroll
      for (int v = 0; v < 4; ++v) {
        const int row = m0 + wm0 + i * 16 + quad * 4 + v;
        float val = acc[i][j][v] * alpha + bvv;
        if (GELU) val = 0.5f * val * (1.0f + erff(val * 0.70710678118654752440f));
        if (RESID) val += b2f(resid[(long)row * ldc + col]);
        Cb[(long)row * ldc + col] = f2b(val);
      }
    }
  }
}

// ------------------------------------------------ fused epipolar attention
// out_a[b][q][h*64+d] = softmax_k( (0.125*q·k) * wm[b][q][k] ) @ V
// 4 waves x 32 q-rows (rows wave-owned), key tiles of 64, online softmax.
__global__ __launch_bounds__(256, 2)
void fattn(const u16* __restrict__ qb, const u16* __restrict__ kb,
           const u16* __restrict__ vT, const u16* __restrict__ wm,
           u16* __restrict__ outA)
{
  __shared__ u16 Qs[128][72];
  __shared__ u16 Ks[64][72];
  __shared__ u16 Vs[64][72];   // V^T tile: [d][key]
  __shared__ u16 Ps[128][72];

  const int bh = blockIdx.y;
  const int b = bh / HEADS, h = bh - b * HEADS;
  const int q0 = blockIdx.x * 128;
  const int tid = threadIdx.x;
  const int lane = tid & 63;
  const int wv = tid >> 6;
  const int wm0 = wv * 32;          // wave owns q-rows [wm0, wm0+32)
  const int l15 = lane & 15;
  const int quad = lane >> 4;

  const u16* Qg = qb + ((long)b * NSEQ + q0) * DIMM + h * DHEAD;
  const u16* Kg = kb + (long)b * NSEQ * DIMM + h * DHEAD;
  const u16* Vg = vT + (long)bh * DHEAD * NSEQ;
  const u16* Wg = wm + (long)b * NSEQ * NSEQ;

  // stage Q once (128 x 64)
  #pragma unroll
  for (int t = 0; t < 4; ++t) {
    const int slot = tid + 256 * t;
    const int r = slot >> 3, c8 = (slot & 7) * 8;
    *(u16x8*)&Qs[r][c8] = *(const u16x8*)&Qg[(long)r * DIMM + c8];
  }

  f32x4 Sacc[2][4], Oacc[2][4];
  float mrow[2][4], lrow[2][4];
  #pragma unroll
  for (int i = 0; i < 2; ++i)
    #pragma unroll
    for (int j = 0; j < 4; ++j) {
      Oacc[i][j] = {0.f, 0.f, 0.f, 0.f};
      mrow[i][j] = -3.0e38f;
      lrow[i][j] = 0.f;
    }

  s16x8 qf[2][2];
  bool qf_loaded = false;

  for (int kt = 0; kt < 16; ++kt) {
    __syncthreads();   // prior PV reads of Vs/Ps done
    #pragma unroll
    for (int t = 0; t < 2; ++t) {
      const int slot = tid + 256 * t;
      const int r = slot >> 3, c8 = (slot & 7) * 8;
      *(u16x8*)&Ks[r][c8] = *(const u16x8*)&Kg[(long)(kt * 64 + r) * DIMM + c8];
      *(u16x8*)&Vs[r][c8] = *(const u16x8*)&Vg[(long)r * NSEQ + kt * 64 + c8];
    }
    __syncthreads();

    if (!qf_loaded) {
      #pragma unroll
      for (int i = 0; i < 2; ++i)
        #pragma unroll
        for (int ks = 0; ks < 2; ++ks)
          qf[i][ks] = *(const s16x8*)&Qs[wm0 + i * 16 + l15][ks * 32 + quad * 8];
      qf_loaded = true;
    }

    // S = Q @ K^T  (32 q-rows x 64 keys per wave)
    #pragma unroll
    for (int i = 0; i < 2; ++i)
      #pragma unroll
      for (int j = 0; j < 4; ++j)
        Sacc[i][j] = {0.f, 0.f, 0.f, 0.f};
    #pragma unroll
    for (int j = 0; j < 4; ++j)
      #pragma unroll
      for (int ks = 0; ks < 2; ++ks) {
        s16x8 kf = *(const s16x8*)&Ks[j * 16 + l15][ks * 32 + quad * 8];
        #pragma unroll
        for (int i = 0; i < 2; ++i)
          Sacc[i][j] = __builtin_amdgcn_mfma_f32_16x16x32_bf16(qf[i][ks], kf, Sacc[i][j], 0, 0, 0);
      }

    // p = 0.125*S*w ; online softmax
    #pragma unroll
    for (int i = 0; i < 2; ++i) {
      const int rbase = q0 + wm0 + i * 16 + quad * 4;
      #pragma unroll
      for (int j = 0; j < 4; ++j) {
        const long cidx = (long)kt * 64 + j * 16 + l15;
        #pragma unroll
        for (int v = 0; v < 4; ++v) {
          const float w = b2f(Wg[(long)(rbase + v) * NSEQ + cidx]);
          Sacc[i][j][v] = Sacc[i][j][v] * 0.125f * w;
        }
      }
      #pragma unroll
      for (int v = 0; v < 4; ++v) {
        float tm = fmaxf(fmaxf(Sacc[i][0][v], Sacc[i][1][v]),
                         fmaxf(Sacc[i][2][v], Sacc[i][3][v]));
        tm = fmaxf(tm, __shfl_xor(tm, 1));
        tm = fmaxf(tm, __shfl_xor(tm, 2));
        tm = fmaxf(tm, __shfl_xor(tm, 4));
        tm = fmaxf(tm, __shfl_xor(tm, 8));
        const float mnew = fmaxf(mrow[i][v], tm);
        const float alpha = expf(mrow[i][v] - mnew);
        float rs = 0.f;
        #pragma unroll
        for (int j = 0; j < 4; ++j) {
          const float e = expf(Sacc[i][j][v] - mnew);
          Sacc[i][j][v] = e;
          rs += e;
        }
        rs += __shfl_xor(rs, 1);
        rs += __shfl_xor(rs, 2);
        rs += __shfl_xor(rs, 4);
        rs += __shfl_xor(rs, 8);
        lrow[i][v] = lrow[i][v] * alpha + rs;
        mrow[i][v] = mnew;
        #pragma unroll
        for (int jn = 0; jn < 4; ++jn)
          Oacc[i][jn][v] *= alpha;
      }
      // write P tile (bf16, C-layout position)
      #pragma unroll
      for (int j = 0; j < 4; ++j)
        #pragma unroll
        for (int v = 0; v < 4; ++v)
          Ps[wm0 + i * 16 + quad * 4 + v][j * 16 + l15] = f2b(Sacc[i][j][v]);
    }
    __syncthreads();

    // O += P @ V   (P: A-layout from LDS; V^T tile is the BT operand)
    #pragma unroll
    for (int ks = 0; ks < 2; ++ks) {
      s16x8 af0 = *(const s16x8*)&Ps[wm0 + l15][ks * 32 + quad * 8];
      s16x8 af1 = *(const s16x8*)&Ps[wm0 + 16 + l15][ks * 32 + quad * 8];
      #pragma unroll
      for (int jn = 0; jn < 4; ++jn) {
        s16x8 bfr = *(const s16x8*)&Vs[jn * 16 + l15][ks * 32 + quad * 8];
        Oacc[0][jn] = __builtin_amdgcn_mfma_f32_16x16x32_bf16(af0, bfr, Oacc[0][jn], 0, 0, 0);
        Oacc[1][jn] = __builtin_amdgcn_mfma_f32_16x16x32_bf16(af1, bfr, Oacc[1][jn], 0, 0, 0);
      }
    }
  }

  // epilogue: a = O / l
  #pragma unroll
  for (int i = 0; i < 2; ++i)
    #pragma unroll
    for (int v = 0; v < 4; ++v) {
      const int row = wm0 + i * 16 + quad * 4 + v;
      const float inv = 1.0f / lrow[i][v];
      #pragma unroll
      for (int jn = 0; jn < 4; ++jn) {
        const int d = jn * 16 + l15;
        outA[((long)(b * NSEQ + q0 + row)) * DIMM + h * DHEAD + d] =
            f2b(Oacc[i][jn][v] * inv);
      }
    }
}

// ---------------------------------------------------------------- LayerNorm
template<bool F32OUT>
__global__ __launch_bounds__(256)
void ln_kernel(const void* __restrict__ in, const void* __restrict__ g,
               const void* __restrict__ bb, void* __restrict__ out,
               const int* __restrict__ flIn, const int* __restrict__ flGB)
{
  const bool fI = *flIn != 0;
  const bool fG = *flGB != 0;
  const long row = blockIdx.x;
  const long base = row * DIMM;
  const int tid = threadIdx.x;
  __shared__ float s1[8], s2[8];
  float v0 = ld(in, base + tid, fI);
  float v1 = ld(in, base + tid + 256, fI);
  float v2 = ld(in, base + tid + 512, fI);
  float s = v0 + v1 + v2;
  #pragma unroll
  for (int off = 32; off; off >>= 1) s += __shfl_down(s, off);
  const int lane = tid & 63, wid = tid >> 6;
  if (!lane) s1[wid] = s;
  __syncthreads();
  if (!tid) s1[4] = s1[0] + s1[1] + s1[2] + s1[3];
  __syncthreads();
  const float mu = s1[4] / 768.0f;
  float d0 = v0 - mu, d1 = v1 - mu, d2 = v2 - mu;
  float sq = d0 * d0 + d1 * d1 + d2 * d2;
  #pragma unroll
  for (int off = 32; off; off >>= 1) sq += __shfl_down(sq, off);
  if (!lane) s2[wid] = sq;
  __syncthreads();
  if (!tid) s2[4] = s2[0] + s2[1] + s2[2] + s2[3];
  __syncthreads();
  const float var = s2[4] / 768.0f;
  const float rstd = 1.0f / sqrtf(var + 1e-5f);
  float o0 = d0 * rstd * ld(g, tid, fG)       + ld(bb, tid, fG);
  float o1 = d1 * rstd * ld(g, tid + 256, fG) + ld(bb, tid + 256, fG);
  float o2 = d2 * rstd * ld(g, tid + 512, fG) + ld(bb, tid + 512, fG);
  if (F32OUT) {
    float* o = (float*)out + base;
    o[tid] = o0; o[tid + 256] = o1; o[tid + 512] = o2;
  } else {
    u16* o = (u16*)out + base;
    o[tid] = f2b(o0); o[tid + 256] = f2b(o1); o[tid + 512] = f2b(o2);
  }
}

// --------------------------------------- weight transpose: raw -> bf16 out
__global__ __launch_bounds__(256)
void transpose_k(const void* __restrict__ in, u16* __restrict__ out, int R, int C,
                 const int* __restrict__ fl)
{
  const bool f32m = *fl != 0;
  __shared__ u16 t[32][36];
  const int c0 = blockIdx.x * 32;
  const int r0 = blockIdx.y * 32;
  const int tid = threadIdx.x;
  const int i = tid >> 3;
  const int j4 = (tid & 7) * 4;
  #pragma unroll
  for (int jj = 0; jj < 4; ++jj)
    t[i][j4 + jj] = f2b(ld(in, (long)(r0 + i) * C + c0 + j4 + jj, f32m));
  __syncthreads();
  u16x4 ov;
  #pragma unroll
  for (int jj = 0; jj < 4; ++jj) ov[jj] = t[j4 + jj][i];
  *(u16x4*)&out[(long)(c0 + i) * R + r0 + j4] = ov;
}

// ------------------------------------------------- V -> vT[bh][d][n] reshape
__global__ __launch_bounds__(256)
void v_transpose(const u16* __restrict__ v, u16* __restrict__ vT)
{
  __shared__ u16 t[64][72];
  const int z = blockIdx.y;
  const int b = z / HEADS, h = z - b * HEADS;
  const int n0 = blockIdx.x * 64;
  const int tid = threadIdx.x;
  const int i = tid >> 2;
  const int jb = (tid & 3) * 16;
  const u16* src = v + (long)(b * NSEQ + n0 + i) * DIMM + h * DHEAD + jb;
  *(u16x8*)&t[i][jb]     = *(const u16x8*)&src[0];
  *(u16x8*)&t[i][jb + 8] = *(const u16x8*)&src[8];
  __syncthreads();
  const int dd = tid >> 2;
  const int nb = (tid & 3) * 16;
  u16x8 o0, o1;
  #pragma unroll
  for (int nn = 0; nn < 8; ++nn) { o0[nn] = t[nb + nn][dd]; o1[nn] = t[nb + 8 + nn][dd]; }
  u16* dst = vT + ((long)z * DHEAD + dd) * NSEQ + n0 + nb;
  *(u16x8*)&dst[0] = o0;
  *(u16x8*)&dst[8] = o1;
}

// ------------------------------------------------------- epipolar: per-batch
__global__ void epi_setup(const void* __restrict__ intr, const void* __restrict__ c2w,
                          float* __restrict__ u4, float* __restrict__ oijb,
                          const int* __restrict__ fl)
{
  const int db = blockIdx.x;
  const int d = db >> 2, b = db & 3;
  __shared__ float S[36];
  if (threadIdx.x == 0) {
    const bool f32m = *fl != 0;
    const int sidx = (d == 0) ? 1 : 0;
    const int tidx = 1 - sidx;
    float k3[9], sr[9], st[3], tr[9], tt[3];
    const float Wf = 32.0f * 16.0f / 9.0f;
    for (int j = 0; j < 3; ++j) {
      k3[j]     = ld(intr, (b * 4 + 0) * 4 + j, f32m) * Wf;
      k3[3 + j] = ld(intr, (b * 4 + 1) * 4 + j, f32m) * 32.0f;
      k3[6 + j] = ld(intr, (b * 4 + 2) * 4 + j, f32m);
    }
    k3[2] = 16.0f; k3[5] = 16.0f;
    for (int i = 0; i < 3; ++i) {
      for (int j = 0; j < 3; ++j) {
        sr[i * 3 + j] = ld(c2w, ((sidx * 4 + b) * 4 + i) * 4 + j, f32m);
        tr[i * 3 + j] = ld(c2w, ((tidx * 4 + b) * 4 + i) * 4 + j, f32m);
      }
      st[i] = ld(c2w, ((sidx * 4 + b) * 4 + i) * 4 + 3, f32m);
      tt[i] = ld(c2w, ((tidx * 4 + b) * 4 + i) * 4 + 3, f32m);
    }
    double a = tr[0], bb_ = tr[1], c = tr[2];
    double dd2 = tr[3], e = tr[4], f = tr[5];
    double g2 = tr[6], h2 = tr[7], i2 = tr[8];
    double det = a * (e * i2 - f * h2) - bb_ * (dd2 * i2 - f * g2) + c * (dd2 * h2 - e * g2);
    double inv[9] = {
      (e * i2 - f * h2), (c * h2 - bb_ * i2), (bb_ * f - c * e),
      (f * g2 - dd2 * i2), (a * i2 - c * g2), (c * dd2 - a * f),
      (dd2 * h2 - e * g2), (bb_ * g2 - a * h2), (a * e - bb_ * dd2)
    };
    float tri[9];
    for (int t2 = 0; t2 < 9; ++t2) tri[t2] = (float)(inv[t2] / det);
    float o2[3], oij[3];
    for (int i3 = 0; i3 < 3; ++i3)
      o2[i3] = tri[i3 * 3] * st[0] + tri[i3 * 3 + 1] * st[1] + tri[i3 * 3 + 2] * st[2] - tt[i3];
    for (int i3 = 0; i3 < 3; ++i3)
      oij[i3] = k3[i3 * 3] * o2[0] + k3[i3 * 3 + 1] * o2[1] + k3[i3 * 3 + 2] * o2[2];
    const float ozf = oij[2];
    oij[0] = oij[0] / ozf; oij[1] = oij[1] / ozf; oij[2] = ozf / ozf;
    for (int t2 = 0; t2 < 9; ++t2) { S[t2] = k3[t2]; S[9 + t2] = sr[t2]; S[21 + t2] = tri[t2]; }
    for (int t2 = 0; t2 < 3; ++t2) { S[18 + t2] = st[t2]; S[30 + t2] = tt[t2]; S[33 + t2] = oij[t2]; }
    oijb[db * 4 + 0] = oij[0]; oijb[db * 4 + 1] = oij[1]; oijb[db * 4 + 2] = oij[2];
    oijb[db * 4 + 3] = 0.f;
  }
  __syncthreads();
  for (int n = threadIdx.x; n < 1024; n += blockDim.x) {
    const float ncx = ((float)(n & 31) - S[2]) / S[0];
    const float ncy = ((float)(n >> 5) - S[5]) / S[4];
    const float p0 = S[9]  * ncx + S[10] * ncy + S[11] + S[18];
    const float p1 = S[12] * ncx + S[13] * ncy + S[14] + S[19];
    const float p2 = S[15] * ncx + S[16] * ncy + S[17] + S[20];
    const float q0 = S[21] * p0 + S[22] * p1 + S[23] * p2 - S[30];
    const float q1 = S[24] * p0 + S[25] * p1 + S[26] * p2 - S[31];
    const float q2 = S[27] * p0 + S[28] * p1 + S[29] * p2 - S[32];
    const float w0 = S[0] * q0 + S[1] * q1 + S[2] * q2;
    const float w1 = S[3] * q0 + S[4] * q1 + S[5] * q2;
    const float w2 = S[6] * q0 + S[7] * q1 + S[8] * q2;
    const float pz = w2 + 1e-6f;
    const float ux = w0 / pz - S[33];
    const float uy = w1 / pz - S[34];
    const float uz = w2 / pz - S[35];
    const float vlen = sqrtf(ux * ux + uy * uy + uz * uz);
    f32x4 uo = {ux, uy, uz, vlen};
    *(f32x4*)&u4[((long)db * 1024 + n) * 4] = uo;
  }
}

// -------------------------------------------- epipolar: dw rows (+row where)
__global__ __launch_bounds__(256)
void epi_dw(const float* __restrict__ u4, const float* __restrict__ oijb,
            float* __restrict__ dw)
{
  const int rowid = blockIdx.x;
  const int db = rowid >> 10;
  const f32x4 U = *(const f32x4*)&u4[(long)rowid * 4];
  const float ox = oijb[db * 4 + 0];
  const float oy = oijb[db * 4 + 1];
  const float oz = oijb[db * 4 + 2];
  const int tid = threadIdx.x;
  __shared__ float red[8];
  float vals[4];
  float mx = -1e30f;
  #pragma unroll
  for (int i = 0; i < 4; ++i) {
    const int m = tid + i * 256;
    const float cx = (float)(m & 31) - ox;
    const float cy = (float)(m >> 5) - oy;
    const float cz = 1.0f - oz;
    const float crx = U.y * cz - U.z * cy;
    const float cry = U.z * cx - U.x * cz;
    const float crz = U.x * cy - U.y * cx;
    const float area = sqrtf(crx * crx + cry * cry + crz * crz);
    const float dist = area / U.w;
    const float t = 50.0f * (dist - 0.5f);
    const float dwv = 1.0f - 1.0f / (1.0f + expf(-t));
    vals[i] = dwv;
    mx = fmaxf(mx, dwv);
  }
  #pragma unroll
  for (int off = 32; off; off >>= 1) mx = fmaxf(mx, __shfl_down(mx, off));
  const int lane = tid & 63, wid = tid >> 6;
  if (!lane) red[wid] = mx;
  __syncthreads();
  if (!tid) red[4] = fmaxf(fmaxf(red[0], red[1]), fmaxf(red[2], red[3]));
  __syncthreads();
  const bool fill1 = red[4] < 0.5f;
  float* out = dw + (long)rowid * 1024;
  #pragma unroll
  for (int i = 0; i < 4; ++i)
    out[tid + i * 256] = fill1 ? 1.0f : vals[i];
}

// --------- wmap: bf16 map for fattn + f32 wm_full broadcast (fused output)
__global__ __launch_bounds__(256)
void epi_wmap(const float* __restrict__ dw, u16* __restrict__ wm,
              float* __restrict__ wm_full)
{
  __shared__ float tb[32][33];
  const int b = blockIdx.z;
  const int q0 = blockIdx.x * 32;
  const int k0 = blockIdx.y * 32;
  const int tid = threadIdx.x;
  const int i = tid >> 3;
  const int j4 = (tid & 7) * 4;
  const float* d1 = dw + ((long)(4 + b) * 1024 + (k0 + i)) * 1024 + q0 + j4;
  #pragma unroll
  for (int jj = 0; jj < 4; ++jj) tb[i][j4 + jj] = d1[jj];
  __syncthreads();
  const float* d0 = dw + ((long)b * 1024 + (q0 + i)) * 1024 + k0 + j4;
  u16x4 pk;
  f32x4 wf;
  #pragma unroll
  for (int jj = 0; jj < 4; ++jj) {
    const float w = d0[jj] * tb[j4 + jj][i];
    wf[jj] = w;
    pk[jj] = f2b(w);
  }
  *(u16x4*)&wm[((long)b * 1024 + q0 + i) * 1024 + k0 + j4] = pk;
  #pragma unroll
  for (int h = 0; h < HEADS; ++h)
    *(f32x4*)&wm_full[((long)(b * HEADS + h) * 1024 + q0 + i) * 1024 + k0 + j4] = wf;
}

// ---------------------------------------------------------------------------
extern "C" void kernel_launch(void* const* d_in, const int* in_sizes, int n_in,
                              void* d_out, int out_size, void* d_ws, size_t ws_size,
                              hipStream_t stream)
{
  (void)in_sizes; (void)n_in; (void)out_size; (void)ws_size;
  const void* x     = d_in[0];
  const void* src   = d_in[1];
  const void* intr  = d_in[2];
  const void* c2w   = d_in[3];
  const void* lnq_g = d_in[4];
  const void* lnq_b = d_in[5];
  const void* Wq    = d_in[6];
  const void* bq    = d_in[7];
  const void* lnk_g = d_in[8];
  const void* lnk_b = d_in[9];
  const void* Wk    = d_in[10];
  const void* bk    = d_in[11];
  const void* lnv_g = d_in[12];
  const void* lnv_b = d_in[13];
  const void* Wv    = d_in[14];
  const void* bv    = d_in[15];
  const void* Wp    = d_in[16];
  const void* bp    = d_in[17];
  const void* pre_g = d_in[18];
  const void* pre_b = d_in[19];
  const void* W1    = d_in[20];
  const void* b1    = d_in[21];
  const void* W2    = d_in[22];
  const void* b2    = d_in[23];
  const void* post_g= d_in[24];
  const void* post_b= d_in[25];

  char* ws = (char*)d_ws;
  size_t off = 0;
  auto alloc = [&](size_t bytes) -> char* {
    char* p = ws + off;
    off = (off + bytes + 255) & ~(size_t)255;
    return p;
  };
  const size_t SEQD = (size_t)4096 * 768 * 2;   // 6.29 MB slot

  int* dflag = (int*)alloc(256);
  int* zflag = dflag + 1;
  u16* WqT = (u16*)alloc(768 * 768 * 2);
  u16* WkT = (u16*)alloc(768 * 768 * 2);
  u16* WvT = (u16*)alloc(768 * 768 * 2);
  u16* WpT = (u16*)alloc(768 * 768 * 2);
  u16* W1T = (u16*)alloc(768 * 1536 * 2);
  u16* W2T = (u16*)alloc(1536 * 768 * 2);
  char* pool = alloc(5 * SEQD);                            // 31.5 MB, 5 slots
  float* u4   = (float*)alloc(8 * 1024 * 4 * 4);
  float* oijb = (float*)alloc(8 * 4 * 4);
  u16* wmapb  = (u16*)alloc((size_t)4 * 1024 * 1024 * 2);  // bf16 wmap, 8.4 MB
  float* dwbuf = (float*)alloc((size_t)8 * 1024 * 1024 * 4); // 33.6 MB
  // total ws ~= 83 MB

  u16* S0 = (u16*)pool;                 // LN scratch -> zbuf
  u16* S1 = (u16*)(pool + SEQD);        // qb -> abuf -> t1
  u16* S2 = (u16*)(pool + 2 * SEQD);    // kb -> t0
  u16* S3 = (u16*)(pool + 3 * SEQD);    // vb -> hbuf (S3+S4)
  u16* S4 = (u16*)(pool + 4 * SEQD);    // vT -> hbuf upper half

  // outputs are FLOAT32
  float* out_z  = (float*)d_out;
  float* out_wm = (float*)d_out + (size_t)4 * 1024 * 768;

  detect_dtype<<<1, 64, 0, stream>>>((const unsigned*)lnq_g, dflag);

  // weight transposes
  transpose_k<<<dim3(24, 24), 256, 0, stream>>>(Wq, WqT, 768, 768, dflag);
  transpose_k<<<dim3(24, 24), 256, 0, stream>>>(Wk, WkT, 768, 768, dflag);
  transpose_k<<<dim3(24, 24), 256, 0, stream>>>(Wv, WvT, 768, 768, dflag);
  transpose_k<<<dim3(24, 24), 256, 0, stream>>>(Wp, WpT, 768, 768, dflag);
  transpose_k<<<dim3(48, 24), 256, 0, stream>>>(W1, W1T, 768, 1536, dflag);
  transpose_k<<<dim3(24, 48), 256, 0, stream>>>(W2, W2T, 1536, 768, dflag);

  // epipolar weights: bf16 map + f32 wm_full output (fused)
  epi_setup<<<8, 128, 0, stream>>>(intr, c2w, u4, oijb, dflag);
  epi_dw<<<8192, 256, 0, stream>>>(u4, oijb, dwbuf);
  epi_wmap<<<dim3(32, 32, 4), 256, 0, stream>>>(dwbuf, wmapb, out_wm);

  // Q path
  ln_kernel<false><<<4096, 256, 0, stream>>>(x, lnq_g, lnq_b, S0, dflag, dflag);
  gemm_bt<128,128,false,false><<<dim3(32, 6, 1), 256, 0, stream>>>(
      S0, WqT, bq, nullptr, S1, dflag, 768, 768, 768, 768, 0,0,0,0,0,0, 1.0f);
  // K path
  ln_kernel<false><<<4096, 256, 0, stream>>>(src, lnk_g, lnk_b, S0, dflag, dflag);
  gemm_bt<128,128,false,false><<<dim3(32, 6, 1), 256, 0, stream>>>(
      S0, WkT, bk, nullptr, S2, dflag, 768, 768, 768, 768, 0,0,0,0,0,0, 1.0f);
  // V path
  ln_kernel<false><<<4096, 256, 0, stream>>>(src, lnv_g, lnv_b, S0, dflag, dflag);
  gemm_bt<128,128,false,false><<<dim3(32, 6, 1), 256, 0, stream>>>(
      S0, WvT, bv, nullptr, S3, dflag, 768, 768, 768, 768, 0,0,0,0,0,0, 1.0f);
  v_transpose<<<dim3(16, 48), 256, 0, stream>>>(S3, S4);

  // fused attention: S1(q), S2(k), S4(vT), wmapb -> abuf (S3; vb dead after vT)
  fattn<<<dim3(8, 48), 256, 0, stream>>>(S1, S2, S4, wmapb, S3);

  // proj: t0 (S2) = a @ Wp + bp
  gemm_bt<128,128,false,false><<<dim3(32, 6, 1), 256, 0, stream>>>(
      S3, WpT, bp, nullptr, S2, dflag, 768, 768, 768, 768, 0,0,0,0,0,0, 1.0f);

  // zbuf (S0) = LN(t0)
  ln_kernel<false><<<4096, 256, 0, stream>>>(S2, pre_g, pre_b, S0, zflag, dflag);

  // h (S1 + S4... need 12.6 MB contiguous) -> use S3? S3 holds a (dead after proj).
  // hbuf needs 4096x1536 = 2 slots contiguous: use S3+S4 (a dead, vT dead).
  gemm_bt<128,128,true,false><<<dim3(32, 12, 1), 256, 0, stream>>>(
      S0, W1T, b1, nullptr, S3, dflag, 768, 768, 768, 1536, 0,0,0,0,0,0, 1.0f);

  // t1 (S1) = z + (h @ W2 + b2)
  gemm_bt<128,128,false,true><<<dim3(32, 6, 1), 256, 0, stream>>>(
      S3, W2T, b2, S0, S1, dflag, 1536, 1536, 1536, 768, 0,0,0,0,0,0, 1.0f);

  // out_z = LN(t1)  — f32 output
  ln_kernel<true><<<4096, 256, 0, stream>>>(S1, post_g, post_b, out_z, zflag, dflag);
}

// Round 6
// 578.022 us; speedup vs baseline: 1.1306x; 1.1306x over previous
//
#include <hip/hip_runtime.h>
#include <hip/hip_bf16.h>

typedef unsigned short u16;
typedef __attribute__((ext_vector_type(4))) unsigned short u16x4;
typedef __attribute__((ext_vector_type(8))) unsigned short u16x8;
typedef __attribute__((ext_vector_type(8))) short s16x8;
typedef __attribute__((ext_vector_type(4))) float f32x4;

#define HEADS 12
#define NSEQ 1024
#define DIMM 768
#define DHEAD 64

__device__ __forceinline__ float b2f(u16 h) {
  union { unsigned u; float f; } v; v.u = ((unsigned)h) << 16; return v.f;
}
__device__ __forceinline__ u16 f2b(float f) {
  union { float f; unsigned u; } v; v.f = f;
  unsigned r = v.u + 0x7fffu + ((v.u >> 16) & 1u);
  return (u16)(r >> 16);
}
// async global->LDS, 16B per lane; lds base must be wave-uniform (lane*16 implicit)
__device__ __forceinline__ void gl_lds16(const u16* g, u16* l) {
  __builtin_amdgcn_global_load_lds(
      (const __attribute__((address_space(1))) void*)g,
      (__attribute__((address_space(3))) void*)l, 16, 0, 0);
}

// ---------------------------------------------------------------- GEMM (BT)
// C[m][n] = sum_k A[m][k]*BT[n][k] + bias[n] (GELU?) (+resid?) ; A,BT,C bf16.
// m97 structure: 128x128 tile, BK=32, flat 64B LDS rows, global_load_lds x16.
template<bool GELU, bool RESID>
__global__ __launch_bounds__(256)
void gemm_bt(const u16* __restrict__ A, const u16* __restrict__ BT,
             const float* __restrict__ bias, const u16* __restrict__ resid,
             u16* __restrict__ C, int K, int lda, int ldb, int ldc)
{
  constexpr int BK = 32;
  __shared__ u16 As[128 * BK];
  __shared__ u16 Bs[128 * BK];

  const int m0 = blockIdx.x * 128;
  const int n0 = blockIdx.y * 128;
  const int tid = threadIdx.x;
  const int lane = tid & 63;
  const int wv = tid >> 6;
  const int wm0 = (wv >> 1) * 64;
  const int wn0 = (wv & 1) * 64;
  const int l15 = lane & 15;
  const int quad = lane >> 4;
  const int srow = lane >> 2;        // 0..15 within a 16-row staging group
  const int scol = (lane & 3) * 8;   // 0,8,16,24

  f32x4 acc[4][4];
  #pragma unroll
  for (int i = 0; i < 4; ++i)
    #pragma unroll
    for (int j = 0; j < 4; ++j)
      acc[i][j] = {0.f, 0.f, 0.f, 0.f};

  // lane-level global bases; LDS dests are wave-uniform (lane*16B implicit)
  const u16* Ab = A + (long)(m0 + wv * 32 + srow) * lda + scol;
  const u16* Bb = BT + (long)(n0 + wv * 32 + srow) * ldb + scol;
  u16* AsW = As + (wv * 32) * BK;
  u16* BsW = Bs + (wv * 32) * BK;

  for (int k0 = 0; k0 < K; k0 += BK) {
    __syncthreads();
    #pragma unroll
    for (int t = 0; t < 2; ++t) {
      gl_lds16(Ab + k0 + (long)t * 16 * lda, AsW + t * 16 * BK);
      gl_lds16(Bb + k0 + (long)t * 16 * ldb, BsW + t * 16 * BK);
    }
    __syncthreads();

    s16x8 af[4], bfr[4];
    #pragma unroll
    for (int i = 0; i < 4; ++i)
      af[i] = *(const s16x8*)&As[(wm0 + i * 16 + l15) * BK + quad * 8];
    #pragma unroll
    for (int j = 0; j < 4; ++j)
      bfr[j] = *(const s16x8*)&Bs[(wn0 + j * 16 + l15) * BK + quad * 8];
    #pragma unroll
    for (int i = 0; i < 4; ++i)
      #pragma unroll
      for (int j = 0; j < 4; ++j)
        acc[i][j] = __builtin_amdgcn_mfma_f32_16x16x32_bf16(af[i], bfr[j], acc[i][j], 0, 0, 0);
  }

  #pragma unroll
  for (int i = 0; i < 4; ++i)
    #pragma unroll
    for (int j = 0; j < 4; ++j) {
      const int col = n0 + wn0 + j * 16 + l15;
      const float bvv = bias[col];
      #pragma unroll
      for (int v = 0; v < 4; ++v) {
        const int row = m0 + wm0 + i * 16 + quad * 4 + v;
        float val = acc[i][j][v] + bvv;
        if (GELU) val = 0.5f * val * (1.0f + erff(val * 0.70710678118654752440f));
        if (RESID) val += b2f(resid[(long)row * ldc + col]);
        C[(long)row * ldc + col] = f2b(val);
      }
    }
}

// ------------------------------------------------ fused epipolar attention
// 64 q-rows/block, 4 waves x 16 q-rows, 64-key tiles, online softmax.
// Q/K/V staged via global_load_lds in two 32-col halves (flat 64B rows);
// wmap tile staged wave-privately into padded LDS.
__global__ __launch_bounds__(256, 3)
void fattn(const u16* __restrict__ qb, const u16* __restrict__ kb,
           const u16* __restrict__ vT, const u16* __restrict__ wm,
           u16* __restrict__ outA)
{
  __shared__ u16 Qs[2 * 64 * 32];
  __shared__ u16 Ks[2 * 64 * 32];
  __shared__ u16 Vs[2 * 64 * 32];   // [half][d][key32]
  __shared__ u16 Ws[64][72];        // wmap tile [qrow][key], padded
  __shared__ u16 Ps[64][72];        // P tile, padded

  const int bh = blockIdx.y;
  const int b = bh / HEADS, h = bh - b * HEADS;
  const int q0 = blockIdx.x * 64;
  const int tid = threadIdx.x;
  const int lane = tid & 63;
  const int wv = tid >> 6;
  const int l15 = lane & 15;
  const int quad = lane >> 4;
  const int srow = lane >> 2;
  const int scol = (lane & 3) * 8;

  const u16* Qg = qb + ((long)b * NSEQ + q0) * DIMM + h * DHEAD;
  const u16* Kg = kb + (long)b * NSEQ * DIMM + h * DHEAD;
  const u16* Vg = vT + (long)bh * DHEAD * NSEQ;
  const u16* Wg = wm + ((long)b * NSEQ + q0) * NSEQ;

  // stage Q once (64x64, two 32-col halves)
  #pragma unroll
  for (int h2 = 0; h2 < 2; ++h2)
    gl_lds16(Qg + (long)(wv * 16 + srow) * DIMM + h2 * 32 + scol,
             Qs + (h2 * 64 + wv * 16) * 32);

  f32x4 Sacc[4], Oacc[4];
  float mrow[4], lrow[4];
  #pragma unroll
  for (int j = 0; j < 4; ++j) {
    Oacc[j] = {0.f, 0.f, 0.f, 0.f};
    mrow[j] = -3.0e38f;
    lrow[j] = 0.f;
  }
  s16x8 qf[2];

  for (int kt = 0; kt < 16; ++kt) {
    __syncthreads();   // prior tile reads done
    #pragma unroll
    for (int h2 = 0; h2 < 2; ++h2) {
      gl_lds16(Kg + (long)(kt * 64 + wv * 16 + srow) * DIMM + h2 * 32 + scol,
               Ks + (h2 * 64 + wv * 16) * 32);
      gl_lds16(Vg + (long)(wv * 16 + srow) * NSEQ + kt * 64 + h2 * 32 + scol,
               Vs + (h2 * 64 + wv * 16) * 32);
    }
    // wmap: wave-private rows [wv*16, wv*16+16)
    #pragma unroll
    for (int t = 0; t < 2; ++t) {
      const int col = (lane & 3) * 16 + t * 8;
      u16x8 wvv = *(const u16x8*)&Wg[(long)(wv * 16 + srow) * NSEQ + kt * 64 + col];
      *(u16x8*)&Ws[wv * 16 + srow][col] = wvv;
    }
    __syncthreads();   // staging drained

    if (kt == 0) {
      qf[0] = *(const s16x8*)&Qs[(0 * 64 + wv * 16 + l15) * 32 + quad * 8];
      qf[1] = *(const s16x8*)&Qs[(1 * 64 + wv * 16 + l15) * 32 + quad * 8];
    }

    // S = Q @ K^T (16 q-rows x 64 keys per wave)
    #pragma unroll
    for (int j = 0; j < 4; ++j) Sacc[j] = {0.f, 0.f, 0.f, 0.f};
    #pragma unroll
    for (int j = 0; j < 4; ++j)
      #pragma unroll
      for (int h2 = 0; h2 < 2; ++h2) {
        s16x8 kf = *(const s16x8*)&Ks[(h2 * 64 + j * 16 + l15) * 32 + quad * 8];
        Sacc[j] = __builtin_amdgcn_mfma_f32_16x16x32_bf16(qf[h2], kf, Sacc[j], 0, 0, 0);
      }

    // p = 0.125*S*w ; online softmax (row = wv*16 + quad*4 + v, col = j*16+l15)
    #pragma unroll
    for (int j = 0; j < 4; ++j)
      #pragma unroll
      for (int v = 0; v < 4; ++v)
        Sacc[j][v] *= 0.125f * b2f(Ws[wv * 16 + quad * 4 + v][j * 16 + l15]);
    #pragma unroll
    for (int v = 0; v < 4; ++v) {
      float tm = fmaxf(fmaxf(Sacc[0][v], Sacc[1][v]), fmaxf(Sacc[2][v], Sacc[3][v]));
      tm = fmaxf(tm, __shfl_xor(tm, 1));
      tm = fmaxf(tm, __shfl_xor(tm, 2));
      tm = fmaxf(tm, __shfl_xor(tm, 4));
      tm = fmaxf(tm, __shfl_xor(tm, 8));
      const float mnew = fmaxf(mrow[v], tm);
      const float al = __expf(mrow[v] - mnew);
      float rs = 0.f;
      #pragma unroll
      for (int j = 0; j < 4; ++j) {
        const float e = __expf(Sacc[j][v] - mnew);
        Sacc[j][v] = e;
        rs += e;
      }
      rs += __shfl_xor(rs, 1);
      rs += __shfl_xor(rs, 2);
      rs += __shfl_xor(rs, 4);
      rs += __shfl_xor(rs, 8);
      lrow[v] = lrow[v] * al + rs;
      mrow[v] = mnew;
      #pragma unroll
      for (int jn = 0; jn < 4; ++jn) Oacc[jn][v] *= al;
    }
    // P -> LDS (C-layout position); read back only by the same wave
    #pragma unroll
    for (int j = 0; j < 4; ++j)
      #pragma unroll
      for (int v = 0; v < 4; ++v)
        Ps[wv * 16 + quad * 4 + v][j * 16 + l15] = f2b(Sacc[j][v]);

    // O += P @ V
    #pragma unroll
    for (int h2 = 0; h2 < 2; ++h2) {
      s16x8 af = *(const s16x8*)&Ps[wv * 16 + l15][h2 * 32 + quad * 8];
      #pragma unroll
      for (int jn = 0; jn < 4; ++jn) {
        s16x8 vf = *(const s16x8*)&Vs[(h2 * 64 + jn * 16 + l15) * 32 + quad * 8];
        Oacc[jn] = __builtin_amdgcn_mfma_f32_16x16x32_bf16(af, vf, Oacc[jn], 0, 0, 0);
      }
    }
  }

  // epilogue: a = O / l
  #pragma unroll
  for (int v = 0; v < 4; ++v) {
    const int row = q0 + wv * 16 + quad * 4 + v;
    const float inv = 1.0f / lrow[v];
    #pragma unroll
    for (int jn = 0; jn < 4; ++jn)
      outA[((long)(b * NSEQ + row)) * DIMM + h * DHEAD + jn * 16 + l15] =
          f2b(Oacc[jn][v] * inv);
  }
}

// ---------------------------------------------------------------- LayerNorm
template<bool F32IN, bool F32OUT>
__global__ __launch_bounds__(256)
void ln_kernel(const void* __restrict__ in, const float* __restrict__ g,
               const float* __restrict__ bb, void* __restrict__ out)
{
  const long base = (long)blockIdx.x * DIMM;
  const int tid = threadIdx.x;
  __shared__ float s1[8], s2[8];
  float v0, v1, v2;
  if (F32IN) {
    const float* p = (const float*)in + base;
    v0 = p[tid]; v1 = p[tid + 256]; v2 = p[tid + 512];
  } else {
    const u16* p = (const u16*)in + base;
    v0 = b2f(p[tid]); v1 = b2f(p[tid + 256]); v2 = b2f(p[tid + 512]);
  }
  float s = v0 + v1 + v2;
  #pragma unroll
  for (int off = 32; off; off >>= 1) s += __shfl_down(s, off);
  const int lane = tid & 63, wid = tid >> 6;
  if (!lane) s1[wid] = s;
  __syncthreads();
  if (!tid) s1[4] = s1[0] + s1[1] + s1[2] + s1[3];
  __syncthreads();
  const float mu = s1[4] / 768.0f;
  float d0 = v0 - mu, d1 = v1 - mu, d2 = v2 - mu;
  float sq = d0 * d0 + d1 * d1 + d2 * d2;
  #pragma unroll
  for (int off = 32; off; off >>= 1) sq += __shfl_down(sq, off);
  if (!lane) s2[wid] = sq;
  __syncthreads();
  if (!tid) s2[4] = s2[0] + s2[1] + s2[2] + s2[3];
  __syncthreads();
  const float rstd = 1.0f / sqrtf(s2[4] / 768.0f + 1e-5f);
  float o0 = d0 * rstd * g[tid]       + bb[tid];
  float o1 = d1 * rstd * g[tid + 256] + bb[tid + 256];
  float o2 = d2 * rstd * g[tid + 512] + bb[tid + 512];
  if (F32OUT) {
    float* o = (float*)out + base;
    o[tid] = o0; o[tid + 256] = o1; o[tid + 512] = o2;
  } else {
    u16* o = (u16*)out + base;
    o[tid] = f2b(o0); o[tid + 256] = f2b(o1); o[tid + 512] = f2b(o2);
  }
}

// ---------------------- all 6 weight transposes in one launch (f32 -> bf16)
__global__ __launch_bounds__(256)
void trans_all(const float* w0, const float* w1, const float* w2,
               const float* w3, const float* w4, const float* w5,
               u16* d0, u16* d1, u16* d2, u16* d3, u16* d4, u16* d5)
{
  const float* src; u16* dst; int R, C;
  switch (blockIdx.z) {
    case 0: src = w0; dst = d0; R = 768;  C = 768;  break;
    case 1: src = w1; dst = d1; R = 768;  C = 768;  break;
    case 2: src = w2; dst = d2; R = 768;  C = 768;  break;
    case 3: src = w3; dst = d3; R = 768;  C = 768;  break;
    case 4: src = w4; dst = d4; R = 768;  C = 1536; break;
    default: src = w5; dst = d5; R = 1536; C = 768; break;
  }
  const int c0 = blockIdx.x * 32;
  const int r0 = blockIdx.y * 32;
  if (c0 >= C || r0 >= R) return;
  __shared__ u16 t[32][36];
  const int tid = threadIdx.x;
  const int i = tid >> 3;
  const int j4 = (tid & 7) * 4;
  #pragma unroll
  for (int jj = 0; jj < 4; ++jj)
    t[i][j4 + jj] = f2b(src[(long)(r0 + i) * C + c0 + j4 + jj]);
  __syncthreads();
  u16x4 ov;
  #pragma unroll
  for (int jj = 0; jj < 4; ++jj) ov[jj] = t[j4 + jj][i];
  *(u16x4*)&dst[(long)(c0 + i) * R + r0 + j4] = ov;
}

// ------------------------------------------------- V -> vT[bh][d][n] reshape
__global__ __launch_bounds__(256)
void v_transpose(const u16* __restrict__ v, u16* __restrict__ vT)
{
  __shared__ u16 t[64][72];
  const int z = blockIdx.y;
  const int b = z / HEADS, h = z - b * HEADS;
  const int n0 = blockIdx.x * 64;
  const int tid = threadIdx.x;
  const int i = tid >> 2;
  const int jb = (tid & 3) * 16;
  const u16* src = v + (long)(b * NSEQ + n0 + i) * DIMM + h * DHEAD + jb;
  *(u16x8*)&t[i][jb]     = *(const u16x8*)&src[0];
  *(u16x8*)&t[i][jb + 8] = *(const u16x8*)&src[8];
  __syncthreads();
  const int dd = tid >> 2;
  const int nb = (tid & 3) * 16;
  u16x8 o0, o1;
  #pragma unroll
  for (int nn = 0; nn < 8; ++nn) { o0[nn] = t[nb + nn][dd]; o1[nn] = t[nb + 8 + nn][dd]; }
  u16* dst = vT + ((long)z * DHEAD + dd) * NSEQ + n0 + nb;
  *(u16x8*)&dst[0] = o0;
  *(u16x8*)&dst[8] = o1;
}

// ------------------------------------------------------- epipolar: per-batch
__global__ void epi_setup(const float* __restrict__ intr, const float* __restrict__ c2w,
                          float* __restrict__ u4, float* __restrict__ oijb)
{
  const int db = blockIdx.x;
  const int d = db >> 2, b = db & 3;
  __shared__ float S[36];
  if (threadIdx.x == 0) {
    const int sidx = (d == 0) ? 1 : 0;
    const int tidx = 1 - sidx;
    float k3[9], sr[9], st[3], tr[9], tt[3];
    const float Wf = 32.0f * 16.0f / 9.0f;
    for (int j = 0; j < 3; ++j) {
      k3[j]     = intr[(b * 4 + 0) * 4 + j] * Wf;
      k3[3 + j] = intr[(b * 4 + 1) * 4 + j] * 32.0f;
      k3[6 + j] = intr[(b * 4 + 2) * 4 + j];
    }
    k3[2] = 16.0f; k3[5] = 16.0f;
    for (int i = 0; i < 3; ++i) {
      for (int j = 0; j < 3; ++j) {
        sr[i * 3 + j] = c2w[((sidx * 4 + b) * 4 + i) * 4 + j];
        tr[i * 3 + j] = c2w[((tidx * 4 + b) * 4 + i) * 4 + j];
      }
      st[i] = c2w[((sidx * 4 + b) * 4 + i) * 4 + 3];
      tt[i] = c2w[((tidx * 4 + b) * 4 + i) * 4 + 3];
    }
    double a = tr[0], bb_ = tr[1], c = tr[2];
    double dd2 = tr[3], e = tr[4], f = tr[5];
    double g2 = tr[6], h2 = tr[7], i2 = tr[8];
    double det = a * (e * i2 - f * h2) - bb_ * (dd2 * i2 - f * g2) + c * (dd2 * h2 - e * g2);
    double inv[9] = {
      (e * i2 - f * h2), (c * h2 - bb_ * i2), (bb_ * f - c * e),
      (f * g2 - dd2 * i2), (a * i2 - c * g2), (c * dd2 - a * f),
      (dd2 * h2 - e * g2), (bb_ * g2 - a * h2), (a * e - bb_ * dd2)
    };
    float tri[9];
    for (int t2 = 0; t2 < 9; ++t2) tri[t2] = (float)(inv[t2] / det);
    float o2[3], oij[3];
    for (int i3 = 0; i3 < 3; ++i3)
      o2[i3] = tri[i3 * 3] * st[0] + tri[i3 * 3 + 1] * st[1] + tri[i3 * 3 + 2] * st[2] - tt[i3];
    for (int i3 = 0; i3 < 3; ++i3)
      oij[i3] = k3[i3 * 3] * o2[0] + k3[i3 * 3 + 1] * o2[1] + k3[i3 * 3 + 2] * o2[2];
    const float ozf = oij[2];
    oij[0] = oij[0] / ozf; oij[1] = oij[1] / ozf; oij[2] = ozf / ozf;
    for (int t2 = 0; t2 < 9; ++t2) { S[t2] = k3[t2]; S[9 + t2] = sr[t2]; S[21 + t2] = tri[t2]; }
    for (int t2 = 0; t2 < 3; ++t2) { S[18 + t2] = st[t2]; S[30 + t2] = tt[t2]; S[33 + t2] = oij[t2]; }
    oijb[db * 4 + 0] = oij[0]; oijb[db * 4 + 1] = oij[1]; oijb[db * 4 + 2] = oij[2];
    oijb[db * 4 + 3] = 0.f;
  }
  __syncthreads();
  for (int n = threadIdx.x; n < 1024; n += blockDim.x) {
    const float ncx = ((float)(n & 31) - S[2]) / S[0];
    const float ncy = ((float)(n >> 5) - S[5]) / S[4];
    const float p0 = S[9]  * ncx + S[10] * ncy + S[11] + S[18];
    const float p1 = S[12] * ncx + S[13] * ncy + S[14] + S[19];
    const float p2 = S[15] * ncx + S[16] * ncy + S[17] + S[20];
    const float q0 = S[21] * p0 + S[22] * p1 + S[23] * p2 - S[30];
    const float q1 = S[24] * p0 + S[25] * p1 + S[26] * p2 - S[31];
    const float q2 = S[27] * p0 + S[28] * p1 + S[29] * p2 - S[32];
    const float w0 = S[0] * q0 + S[1] * q1 + S[2] * q2;
    const float w1 = S[3] * q0 + S[4] * q1 + S[5] * q2;
    const float w2 = S[6] * q0 + S[7] * q1 + S[8] * q2;
    const float pz = w2 + 1e-6f;
    const float ux = w0 / pz - S[33];
    const float uy = w1 / pz - S[34];
    const float uz = w2 / pz - S[35];
    const float vlen = sqrtf(ux * ux + uy * uy + uz * uz);
    f32x4 uo = {ux, uy, uz, vlen};
    *(f32x4*)&u4[((long)db * 1024 + n) * 4] = uo;
  }
}

// -------------------------------------------- epipolar: dw rows (+row where)
__global__ __launch_bounds__(256)
void epi_dw(const float* __restrict__ u4, const float* __restrict__ oijb,
            float* __restrict__ dw)
{
  const int rowid = blockIdx.x;
  const int db = rowid >> 10;
  const f32x4 U = *(const f32x4*)&u4[(long)rowid * 4];
  const float ox = oijb[db * 4 + 0];
  const float oy = oijb[db * 4 + 1];
  const float oz = oijb[db * 4 + 2];
  const int tid = threadIdx.x;
  __shared__ float red[8];
  float vals[4];
  float mx = -1e30f;
  #pragma unroll
  for (int i = 0; i < 4; ++i) {
    const int m = tid + i * 256;
    const float cx = (float)(m & 31) - ox;
    const float cy = (float)(m >> 5) - oy;
    const float cz = 1.0f - oz;
    const float crx = U.y * cz - U.z * cy;
    const float cry = U.z * cx - U.x * cz;
    const float crz = U.x * cy - U.y * cx;
    const float area = sqrtf(crx * crx + cry * cry + crz * crz);
    const float dist = area / U.w;
    const float t = 50.0f * (dist - 0.5f);
    const float dwv = 1.0f - 1.0f / (1.0f + expf(-t));
    vals[i] = dwv;
    mx = fmaxf(mx, dwv);
  }
  #pragma unroll
  for (int off = 32; off; off >>= 1) mx = fmaxf(mx, __shfl_down(mx, off));
  const int lane = tid & 63, wid = tid >> 6;
  if (!lane) red[wid] = mx;
  __syncthreads();
  if (!tid) red[4] = fmaxf(fmaxf(red[0], red[1]), fmaxf(red[2], red[3]));
  __syncthreads();
  const bool fill1 = red[4] < 0.5f;
  float* out = dw + (long)rowid * 1024;
  #pragma unroll
  for (int i = 0; i < 4; ++i)
    out[tid + i * 256] = fill1 ? 1.0f : vals[i];
}

// --------- wmap: bf16 map for fattn + f32 wm_full output (fused broadcast)
__global__ __launch_bounds__(256)
void epi_wmap(const float* __restrict__ dw, u16* __restrict__ wm,
              float* __restrict__ wm_full)
{
  __shared__ float tb[32][33];
  const int b = blockIdx.z;
  const int q0 = blockIdx.x * 32;
  const int k0 = blockIdx.y * 32;
  const int tid = threadIdx.x;
  const int i = tid >> 3;
  const int j4 = (tid & 7) * 4;
  const float* d1 = dw + ((long)(4 + b) * 1024 + (k0 + i)) * 1024 + q0 + j4;
  #pragma unroll
  for (int jj = 0; jj < 4; ++jj) tb[i][j4 + jj] = d1[jj];
  __syncthreads();
  const float* d0 = dw + ((long)b * 1024 + (q0 + i)) * 1024 + k0 + j4;
  u16x4 pk;
  f32x4 wf;
  #pragma unroll
  for (int jj = 0; jj < 4; ++jj) {
    const float w = d0[jj] * tb[j4 + jj][i];
    wf[jj] = w;
    pk[jj] = f2b(w);
  }
  *(u16x4*)&wm[((long)b * 1024 + q0 + i) * 1024 + k0 + j4] = pk;
  #pragma unroll
  for (int h = 0; h < HEADS; ++h)
    *(f32x4*)&wm_full[((long)(b * HEADS + h) * 1024 + q0 + i) * 1024 + k0 + j4] = wf;
}

// ---------------------------------------------------------------------------
extern "C" void kernel_launch(void* const* d_in, const int* in_sizes, int n_in,
                              void* d_out, int out_size, void* d_ws, size_t ws_size,
                              hipStream_t stream)
{
  (void)in_sizes; (void)n_in; (void)out_size; (void)ws_size;
  const float* x     = (const float*)d_in[0];
  const float* src   = (const float*)d_in[1];
  const float* intr  = (const float*)d_in[2];
  const float* c2w   = (const float*)d_in[3];
  const float* lnq_g = (const float*)d_in[4];
  const float* lnq_b = (const float*)d_in[5];
  const float* Wq    = (const float*)d_in[6];
  const float* bq    = (const float*)d_in[7];
  const float* lnk_g = (const float*)d_in[8];
  const float* lnk_b = (const float*)d_in[9];
  const float* Wk    = (const float*)d_in[10];
  const float* bk    = (const float*)d_in[11];
  const float* lnv_g = (const float*)d_in[12];
  const float* lnv_b = (const float*)d_in[13];
  const float* Wv    = (const float*)d_in[14];
  const float* bv    = (const float*)d_in[15];
  const float* Wp    = (const float*)d_in[16];
  const float* bp    = (const float*)d_in[17];
  const float* pre_g = (const float*)d_in[18];
  const float* pre_b = (const float*)d_in[19];
  const float* W1    = (const float*)d_in[20];
  const float* b1    = (const float*)d_in[21];
  const float* W2    = (const float*)d_in[22];
  const float* b2    = (const float*)d_in[23];
  const float* post_g= (const float*)d_in[24];
  const float* post_b= (const float*)d_in[25];

  char* ws = (char*)d_ws;
  size_t off = 0;
  auto alloc = [&](size_t bytes) -> char* {
    char* p = ws + off;
    off = (off + bytes + 255) & ~(size_t)255;
    return p;
  };
  const size_t SEQD = (size_t)4096 * 768 * 2;   // 6.29 MB slot

  u16* WqT = (u16*)alloc(768 * 768 * 2);
  u16* WkT = (u16*)alloc(768 * 768 * 2);
  u16* WvT = (u16*)alloc(768 * 768 * 2);
  u16* WpT = (u16*)alloc(768 * 768 * 2);
  u16* W1T = (u16*)alloc(768 * 1536 * 2);
  u16* W2T = (u16*)alloc(1536 * 768 * 2);
  char* pool = alloc(5 * SEQD);
  float* u4   = (float*)alloc(8 * 1024 * 4 * 4);
  float* oijb = (float*)alloc(8 * 4 * 4);
  u16* wmapb  = (u16*)alloc((size_t)4 * 1024 * 1024 * 2);
  float* dwbuf = (float*)alloc((size_t)8 * 1024 * 1024 * 4);

  u16* S0 = (u16*)pool;                 // LN out -> zbuf
  u16* S1 = (u16*)(pool + SEQD);        // q -> t1
  u16* S2 = (u16*)(pool + 2 * SEQD);    // k -> t0
  u16* S3 = (u16*)(pool + 3 * SEQD);    // v -> a -> h (S3+S4)
  u16* S4 = (u16*)(pool + 4 * SEQD);    // vT -> h upper

  float* out_z  = (float*)d_out;
  float* out_wm = (float*)d_out + (size_t)4 * 1024 * 768;

  // weight transposes (one launch)
  trans_all<<<dim3(48, 48, 6), 256, 0, stream>>>(
      Wq, Wk, Wv, Wp, W1, W2, WqT, WkT, WvT, WpT, W1T, W2T);

  // epipolar weights -> bf16 map + f32 wm_full output
  epi_setup<<<8, 128, 0, stream>>>(intr, c2w, u4, oijb);
  epi_dw<<<8192, 256, 0, stream>>>(u4, oijb, dwbuf);
  epi_wmap<<<dim3(32, 32, 4), 256, 0, stream>>>(dwbuf, wmapb, out_wm);

  // Q path
  ln_kernel<true, false><<<4096, 256, 0, stream>>>(x, lnq_g, lnq_b, S0);
  gemm_bt<false, false><<<dim3(32, 6), 256, 0, stream>>>(
      S0, WqT, bq, nullptr, S1, 768, 768, 768, 768);
  // K path
  ln_kernel<true, false><<<4096, 256, 0, stream>>>(src, lnk_g, lnk_b, S0);
  gemm_bt<false, false><<<dim3(32, 6), 256, 0, stream>>>(
      S0, WkT, bk, nullptr, S2, 768, 768, 768, 768);
  // V path
  ln_kernel<true, false><<<4096, 256, 0, stream>>>(src, lnv_g, lnv_b, S0);
  gemm_bt<false, false><<<dim3(32, 6), 256, 0, stream>>>(
      S0, WvT, bv, nullptr, S3, 768, 768, 768, 768);
  v_transpose<<<dim3(16, 48), 256, 0, stream>>>(S3, S4);

  // fused attention -> a (S3; v dead after vT)
  fattn<<<dim3(16, 48), 256, 0, stream>>>(S1, S2, S4, wmapb, S3);

  // proj: t0 (S2) = a @ Wp + bp
  gemm_bt<false, false><<<dim3(32, 6), 256, 0, stream>>>(
      S3, WpT, bp, nullptr, S2, 768, 768, 768, 768);

  // z (S0) = LN(t0)
  ln_kernel<false, false><<<4096, 256, 0, stream>>>(S2, pre_g, pre_b, S0);

  // h (S3..S4) = gelu(z @ W1 + b1)
  gemm_bt<true, false><<<dim3(32, 12), 256, 0, stream>>>(
      S0, W1T, b1, nullptr, S3, 768, 768, 768, 1536);

  // t1 (S1) = z + (h @ W2 + b2)
  gemm_bt<false, true><<<dim3(32, 6), 256, 0, stream>>>(
      S3, W2T, b2, S0, S1, 1536, 1536, 1536, 768);

  // out_z = LN(t1), f32
  ln_kernel<false, true><<<4096, 256, 0, stream>>>(S1, post_g, post_b, out_z);
}

// Round 7
// 555.810 us; speedup vs baseline: 1.1758x; 1.0400x over previous
//
#include <hip/hip_runtime.h>
#include <hip/hip_bf16.h>

typedef unsigned short u16;
typedef __attribute__((ext_vector_type(4))) unsigned short u16x4;
typedef __attribute__((ext_vector_type(8))) unsigned short u16x8;
typedef __attribute__((ext_vector_type(8))) short s16x8;
typedef __attribute__((ext_vector_type(4))) float f32x4;

#define HEADS 12
#define NSEQ 1024
#define DIMM 768
#define DHEAD 64

__device__ __forceinline__ float b2f(u16 h) {
  union { unsigned u; float f; } v; v.u = ((unsigned)h) << 16; return v.f;
}
__device__ __forceinline__ u16 f2b(float f) {
  union { float f; unsigned u; } v; v.f = f;
  unsigned r = v.u + 0x7fffu + ((v.u >> 16) & 1u);
  return (u16)(r >> 16);
}
// async global->LDS, 16B/lane; LDS dest = wave-uniform base + lane*16B
__device__ __forceinline__ void gl_lds16(const u16* g, u16* l) {
  __builtin_amdgcn_global_load_lds(
      (const __attribute__((address_space(1))) void*)g,
      (__attribute__((address_space(3))) void*)l, 16, 0, 0);
}

// ------------------------------------------- double-buffered GEMM (BT) body
// C[m][n] = sum_k A[m][k]*BT[n][k] + bias[n], optional GELU / affine-resid.
// As/Bs: 2 buffers of 128x32 u16 each (flat 64B rows).
template<bool GELU, bool RESID>
__device__ __forceinline__ void gemm_body(
    const u16* __restrict__ A, const u16* __restrict__ BT,
    const float* __restrict__ bias, const u16* __restrict__ resid,
    const float* __restrict__ rg, const float* __restrict__ rb,
    u16* __restrict__ C, int K, int lda, int ldb, int ldc,
    int m0, int n0, u16* As, u16* Bs)
{
  const int tid = threadIdx.x;
  const int lane = tid & 63;
  const int wv = tid >> 6;
  const int wm0 = (wv >> 1) * 64;
  const int wn0 = (wv & 1) * 64;
  const int l15 = lane & 15;
  const int quad = lane >> 4;
  const int srow = lane >> 2;
  const int scol = (lane & 3) * 8;

  f32x4 acc[4][4];
  #pragma unroll
  for (int i = 0; i < 4; ++i)
    #pragma unroll
    for (int j = 0; j < 4; ++j)
      acc[i][j] = {0.f, 0.f, 0.f, 0.f};

  const u16* Ab = A + (long)(m0 + wv * 32 + srow) * lda + scol;
  const u16* Bb = BT + (long)(n0 + wv * 32 + srow) * ldb + scol;
  u16* AsW = As + (wv * 32) * 32;
  u16* BsW = Bs + (wv * 32) * 32;

  // preload tile 0 into buffer 0
  #pragma unroll
  for (int t = 0; t < 2; ++t) {
    gl_lds16(Ab + (long)t * 16 * lda, AsW + t * 16 * 32);
    gl_lds16(Bb + (long)t * 16 * ldb, BsW + t * 16 * 32);
  }

  int cur = 0;
  for (int k0 = 0; k0 < K; k0 += 32) {
    __syncthreads();                 // buf[cur] staged (vmcnt drained here)
    if (k0 + 32 < K) {
      const int nxt = cur ^ 1;
      #pragma unroll
      for (int t = 0; t < 2; ++t) {
        gl_lds16(Ab + (k0 + 32) + (long)t * 16 * lda, AsW + nxt * 4096 + t * 16 * 32);
        gl_lds16(Bb + (k0 + 32) + (long)t * 16 * ldb, BsW + nxt * 4096 + t * 16 * 32);
      }
    }
    const u16* Ac = As + cur * 4096;
    const u16* Bc = Bs + cur * 4096;
    s16x8 af[4], bfr[4];
    #pragma unroll
    for (int i = 0; i < 4; ++i)
      af[i] = *(const s16x8*)&Ac[(wm0 + i * 16 + l15) * 32 + quad * 8];
    #pragma unroll
    for (int j = 0; j < 4; ++j)
      bfr[j] = *(const s16x8*)&Bc[(wn0 + j * 16 + l15) * 32 + quad * 8];
    #pragma unroll
    for (int i = 0; i < 4; ++i)
      #pragma unroll
      for (int j = 0; j < 4; ++j)
        acc[i][j] = __builtin_amdgcn_mfma_f32_16x16x32_bf16(af[i], bfr[j], acc[i][j], 0, 0, 0);
    cur ^= 1;
  }

  #pragma unroll
  for (int i = 0; i < 4; ++i)
    #pragma unroll
    for (int j = 0; j < 4; ++j) {
      const int col = n0 + wn0 + j * 16 + l15;
      const float bvv = bias[col];
      #pragma unroll
      for (int v = 0; v < 4; ++v) {
        const int row = m0 + wm0 + i * 16 + quad * 4 + v;
        float val = acc[i][j][v] + bvv;
        if (GELU) val = 0.5f * val * (1.0f + erff(val * 0.70710678118654752440f));
        if (RESID) val += b2f(resid[(long)row * ldc + col]) * rg[col] + rb[col];
        C[(long)row * ldc + col] = f2b(val);
      }
    }
}

template<bool GELU, bool RESID>
__global__ __launch_bounds__(256)
void gemm_one(const u16* __restrict__ A, const u16* __restrict__ BT,
              const float* __restrict__ bias, const u16* __restrict__ resid,
              const float* __restrict__ rg, const float* __restrict__ rb,
              u16* __restrict__ C, int K, int lda, int ldb, int ldc)
{
  __shared__ u16 As[8192], Bs[8192];
  gemm_body<GELU, RESID>(A, BT, bias, resid, rg, rb, C, K, lda, ldb, ldc,
                         blockIdx.x * 128, blockIdx.y * 128, As, Bs);
}

// Q + KV projections in one launch: z=0 -> Q, z=1,2 -> KV halves
__global__ __launch_bounds__(256)
void gemm_qkv(const u16* __restrict__ nx, const u16* __restrict__ ns,
              const u16* __restrict__ qT, const u16* __restrict__ kvT,
              const float* __restrict__ bqf, const float* __restrict__ bkvf,
              u16* __restrict__ qb, u16* __restrict__ kvb)
{
  __shared__ u16 As[8192], Bs[8192];
  const int z = blockIdx.z;
  if (z == 0)
    gemm_body<false, false>(nx, qT, bqf, nullptr, nullptr, nullptr, qb,
                            768, 768, 768, 768,
                            blockIdx.x * 128, blockIdx.y * 128, As, Bs);
  else
    gemm_body<false, false>(ns, kvT, bkvf, nullptr, nullptr, nullptr, kvb,
                            768, 768, 768, 1536,
                            blockIdx.x * 128, (z - 1) * 768 + blockIdx.y * 128, As, Bs);
}

// ------------------------------------------------ fused epipolar attention
// q pre-scaled by 0.125 (folded into Wq). K rows stride 1536 (kv buffer).
__global__ __launch_bounds__(256, 3)
void fattn(const u16* __restrict__ qb, const u16* __restrict__ kvb,
           const u16* __restrict__ vT, const u16* __restrict__ wm,
           u16* __restrict__ outA)
{
  __shared__ u16 Qs[2 * 64 * 32];
  __shared__ u16 Ks[2 * 64 * 32];
  __shared__ u16 Vs[2 * 64 * 32];
  __shared__ u16 Ws[64][72];
  __shared__ u16 Ps[64][72];

  const int bh = blockIdx.y;
  const int b = bh / HEADS, h = bh - b * HEADS;
  const int q0 = blockIdx.x * 64;
  const int tid = threadIdx.x;
  const int lane = tid & 63;
  const int wv = tid >> 6;
  const int l15 = lane & 15;
  const int quad = lane >> 4;
  const int srow = lane >> 2;
  const int scol = (lane & 3) * 8;

  const u16* Qg = qb + ((long)b * NSEQ + q0) * DIMM + h * DHEAD;
  const u16* Kg = kvb + (long)b * NSEQ * 1536 + h * DHEAD;
  const u16* Vg = vT + (long)bh * DHEAD * NSEQ;
  const u16* Wg = wm + ((long)b * NSEQ + q0) * NSEQ;

  #pragma unroll
  for (int h2 = 0; h2 < 2; ++h2)
    gl_lds16(Qg + (long)(wv * 16 + srow) * DIMM + h2 * 32 + scol,
             Qs + (h2 * 64 + wv * 16) * 32);

  f32x4 Sacc[4], Oacc[4];
  float mrow[4], lrow[4];
  #pragma unroll
  for (int j = 0; j < 4; ++j) {
    Oacc[j] = {0.f, 0.f, 0.f, 0.f};
    mrow[j] = -3.0e38f;
    lrow[j] = 0.f;
  }
  s16x8 qf[2];

  for (int kt = 0; kt < 16; ++kt) {
    __syncthreads();
    #pragma unroll
    for (int h2 = 0; h2 < 2; ++h2) {
      gl_lds16(Kg + (long)(kt * 64 + wv * 16 + srow) * 1536 + h2 * 32 + scol,
               Ks + (h2 * 64 + wv * 16) * 32);
      gl_lds16(Vg + (long)(wv * 16 + srow) * NSEQ + kt * 64 + h2 * 32 + scol,
               Vs + (h2 * 64 + wv * 16) * 32);
    }
    #pragma unroll
    for (int t = 0; t < 2; ++t) {
      const int col = (lane & 3) * 16 + t * 8;
      u16x8 wvv = *(const u16x8*)&Wg[(long)(wv * 16 + srow) * NSEQ + kt * 64 + col];
      *(u16x8*)&Ws[wv * 16 + srow][col] = wvv;
    }
    __syncthreads();

    if (kt == 0) {
      qf[0] = *(const s16x8*)&Qs[(0 * 64 + wv * 16 + l15) * 32 + quad * 8];
      qf[1] = *(const s16x8*)&Qs[(1 * 64 + wv * 16 + l15) * 32 + quad * 8];
    }

    #pragma unroll
    for (int j = 0; j < 4; ++j) Sacc[j] = {0.f, 0.f, 0.f, 0.f};
    #pragma unroll
    for (int j = 0; j < 4; ++j)
      #pragma unroll
      for (int h2 = 0; h2 < 2; ++h2) {
        s16x8 kf = *(const s16x8*)&Ks[(h2 * 64 + j * 16 + l15) * 32 + quad * 8];
        Sacc[j] = __builtin_amdgcn_mfma_f32_16x16x32_bf16(qf[h2], kf, Sacc[j], 0, 0, 0);
      }

    #pragma unroll
    for (int j = 0; j < 4; ++j)
      #pragma unroll
      for (int v = 0; v < 4; ++v)
        Sacc[j][v] *= b2f(Ws[wv * 16 + quad * 4 + v][j * 16 + l15]);
    #pragma unroll
    for (int v = 0; v < 4; ++v) {
      float tm = fmaxf(fmaxf(Sacc[0][v], Sacc[1][v]), fmaxf(Sacc[2][v], Sacc[3][v]));
      tm = fmaxf(tm, __shfl_xor(tm, 1));
      tm = fmaxf(tm, __shfl_xor(tm, 2));
      tm = fmaxf(tm, __shfl_xor(tm, 4));
      tm = fmaxf(tm, __shfl_xor(tm, 8));
      const float mnew = fmaxf(mrow[v], tm);
      const float al = __expf(mrow[v] - mnew);
      float rs = 0.f;
      #pragma unroll
      for (int j = 0; j < 4; ++j) {
        const float e = __expf(Sacc[j][v] - mnew);
        Sacc[j][v] = e;
        rs += e;
      }
      rs += __shfl_xor(rs, 1);
      rs += __shfl_xor(rs, 2);
      rs += __shfl_xor(rs, 4);
      rs += __shfl_xor(rs, 8);
      lrow[v] = lrow[v] * al + rs;
      mrow[v] = mnew;
      #pragma unroll
      for (int jn = 0; jn < 4; ++jn) Oacc[jn][v] *= al;
    }
    #pragma unroll
    for (int j = 0; j < 4; ++j)
      #pragma unroll
      for (int v = 0; v < 4; ++v)
        Ps[wv * 16 + quad * 4 + v][j * 16 + l15] = f2b(Sacc[j][v]);

    #pragma unroll
    for (int h2 = 0; h2 < 2; ++h2) {
      s16x8 af = *(const s16x8*)&Ps[wv * 16 + l15][h2 * 32 + quad * 8];
      #pragma unroll
      for (int jn = 0; jn < 4; ++jn) {
        s16x8 vf = *(const s16x8*)&Vs[(h2 * 64 + jn * 16 + l15) * 32 + quad * 8];
        Oacc[jn] = __builtin_amdgcn_mfma_f32_16x16x32_bf16(af, vf, Oacc[jn], 0, 0, 0);
      }
    }
  }

  #pragma unroll
  for (int v = 0; v < 4; ++v) {
    const int row = q0 + wv * 16 + quad * 4 + v;
    const float inv = 1.0f / lrow[v];
    #pragma unroll
    for (int jn = 0; jn < 4; ++jn)
      outA[((long)(b * NSEQ + row)) * DIMM + h * DHEAD + jn * 16 + l15] =
          f2b(Oacc[jn][v] * inv);
  }
}

// ------------------------------------------------- pure row-norm (no affine)
template<bool F32IN>
__global__ __launch_bounds__(256)
void norm_k(const void* __restrict__ in, u16* __restrict__ out)
{
  const long base = (long)blockIdx.x * DIMM;
  const int tid = threadIdx.x;
  __shared__ float s1[8], s2[8];
  float v0, v1, v2;
  if (F32IN) {
    const float* p = (const float*)in + base;
    v0 = p[tid]; v1 = p[tid + 256]; v2 = p[tid + 512];
  } else {
    const u16* p = (const u16*)in + base;
    v0 = b2f(p[tid]); v1 = b2f(p[tid + 256]); v2 = b2f(p[tid + 512]);
  }
  float s = v0 + v1 + v2;
  #pragma unroll
  for (int off = 32; off; off >>= 1) s += __shfl_down(s, off);
  const int lane = tid & 63, wid = tid >> 6;
  if (!lane) s1[wid] = s;
  __syncthreads();
  if (!tid) s1[4] = s1[0] + s1[1] + s1[2] + s1[3];
  __syncthreads();
  const float mu = s1[4] / 768.0f;
  float d0 = v0 - mu, d1 = v1 - mu, d2 = v2 - mu;
  float sq = d0 * d0 + d1 * d1 + d2 * d2;
  #pragma unroll
  for (int off = 32; off; off >>= 1) sq += __shfl_down(sq, off);
  if (!lane) s2[wid] = sq;
  __syncthreads();
  if (!tid) s2[4] = s2[0] + s2[1] + s2[2] + s2[3];
  __syncthreads();
  const float rstd = 1.0f / sqrtf(s2[4] / 768.0f + 1e-5f);
  u16* o = out + base;
  o[tid]       = f2b(d0 * rstd);
  o[tid + 256] = f2b(d1 * rstd);
  o[tid + 512] = f2b(d2 * rstd);
}

// ---------------------------------------- final affine LN: bf16 in, f32 out
__global__ __launch_bounds__(256)
void ln_final(const u16* __restrict__ in, const float* __restrict__ g,
              const float* __restrict__ bb, float* __restrict__ out)
{
  const long base = (long)blockIdx.x * DIMM;
  const int tid = threadIdx.x;
  __shared__ float s1[8], s2[8];
  const u16* p = in + base;
  float v0 = b2f(p[tid]), v1 = b2f(p[tid + 256]), v2 = b2f(p[tid + 512]);
  float s = v0 + v1 + v2;
  #pragma unroll
  for (int off = 32; off; off >>= 1) s += __shfl_down(s, off);
  const int lane = tid & 63, wid = tid >> 6;
  if (!lane) s1[wid] = s;
  __syncthreads();
  if (!tid) s1[4] = s1[0] + s1[1] + s1[2] + s1[3];
  __syncthreads();
  const float mu = s1[4] / 768.0f;
  float d0 = v0 - mu, d1 = v1 - mu, d2 = v2 - mu;
  float sq = d0 * d0 + d1 * d1 + d2 * d2;
  #pragma unroll
  for (int off = 32; off; off >>= 1) sq += __shfl_down(sq, off);
  if (!lane) s2[wid] = sq;
  __syncthreads();
  if (!tid) s2[4] = s2[0] + s2[1] + s2[2] + s2[3];
  __syncthreads();
  const float rstd = 1.0f / sqrtf(s2[4] / 768.0f + 1e-5f);
  float* o = out + base;
  o[tid]       = d0 * rstd * g[tid]       + bb[tid];
  o[tid + 256] = d1 * rstd * g[tid + 256] + bb[tid + 256];
  o[tid + 512] = d2 * rstd * g[tid + 512] + bb[tid + 512];
}

// ---------------- weight transposes with LN-gain row-scale folded (1 launch)
__global__ __launch_bounds__(256)
void trans_all(const float* w0, const float* w1, const float* w2,
               const float* w3, const float* w4, const float* w5,
               const float* gq, const float* gk, const float* gv, const float* gp,
               u16* d0, u16* d12, u16* d3, u16* d4, u16* d5)
{
  const float* src; const float* g; u16* dst; int R, C; float sc = 1.0f;
  switch (blockIdx.z) {
    case 0: src = w0; g = gq; dst = d0;  R = 768;  C = 768;  sc = 0.125f; break;
    case 1: src = w1; g = gk; dst = d12; R = 768;  C = 768;  break;
    case 2: src = w2; g = gv; dst = d12 + 768 * 768; R = 768; C = 768; break;
    case 3: src = w3; g = nullptr; dst = d3; R = 768;  C = 768;  break;
    case 4: src = w4; g = gp; dst = d4; R = 768;  C = 1536; break;
    default: src = w5; g = nullptr; dst = d5; R = 1536; C = 768; break;
  }
  const int c0 = blockIdx.x * 32;
  const int r0 = blockIdx.y * 32;
  if (c0 >= C || r0 >= R) return;
  __shared__ u16 t[32][36];
  const int tid = threadIdx.x;
  const int i = tid >> 3;
  const int j4 = (tid & 7) * 4;
  const float rs = (g ? g[r0 + i] : 1.0f) * sc;
  #pragma unroll
  for (int jj = 0; jj < 4; ++jj)
    t[i][j4 + jj] = f2b(src[(long)(r0 + i) * C + c0 + j4 + jj] * rs);
  __syncthreads();
  u16x4 ov;
  #pragma unroll
  for (int jj = 0; jj < 4; ++jj) ov[jj] = t[j4 + jj][i];
  *(u16x4*)&dst[(long)(c0 + i) * R + r0 + j4] = ov;
}

// ---------------- bias folds: b' = (b_w + b_ln @ W) * scale   (1 launch)
__global__ __launch_bounds__(256)
void biasfold(const float* Wq, const float* Wk, const float* Wv, const float* W1,
              const float* bq, const float* bk, const float* bv, const float* b1,
              const float* lnqb, const float* lnkb, const float* lnvb, const float* preb,
              float* obq, float* obkv, float* ob1)
{
  const int y = blockIdx.y;
  const int c = blockIdx.x * 256 + threadIdx.x;
  const float* W; const float* bln; const float* bw; float* out;
  int C; float sc = 1.0f;
  switch (y) {
    case 0: W = Wq; bln = lnqb; bw = bq; out = obq;        C = 768;  sc = 0.125f; break;
    case 1: W = Wk; bln = lnkb; bw = bk; out = obkv;       C = 768;  break;
    case 2: W = Wv; bln = lnvb; bw = bv; out = obkv + 768; C = 768;  break;
    default: W = W1; bln = preb; bw = b1; out = ob1;       C = 1536; break;
  }
  if (c >= C) return;
  float s = bw[c];
  for (int r = 0; r < 768; ++r) s += bln[r] * W[(long)r * C + c];
  out[c] = s * sc;
}

// ------------------------------------------------- V -> vT[bh][d][n] reshape
__global__ __launch_bounds__(256)
void v_transpose(const u16* __restrict__ kvb, u16* __restrict__ vT)
{
  __shared__ u16 t[64][72];
  const int z = blockIdx.y;
  const int b = z / HEADS, h = z - b * HEADS;
  const int n0 = blockIdx.x * 64;
  const int tid = threadIdx.x;
  const int i = tid >> 2;
  const int jb = (tid & 3) * 16;
  const u16* src = kvb + (long)(b * NSEQ + n0 + i) * 1536 + 768 + h * DHEAD + jb;
  *(u16x8*)&t[i][jb]     = *(const u16x8*)&src[0];
  *(u16x8*)&t[i][jb + 8] = *(const u16x8*)&src[8];
  __syncthreads();
  const int dd = tid >> 2;
  const int nb = (tid & 3) * 16;
  u16x8 o0, o1;
  #pragma unroll
  for (int nn = 0; nn < 8; ++nn) { o0[nn] = t[nb + nn][dd]; o1[nn] = t[nb + 8 + nn][dd]; }
  u16* dst = vT + ((long)z * DHEAD + dd) * NSEQ + n0 + nb;
  *(u16x8*)&dst[0] = o0;
  *(u16x8*)&dst[8] = o1;
}

// ------------------------------------------------------- epipolar: per-batch
__global__ void epi_setup(const float* __restrict__ intr, const float* __restrict__ c2w,
                          float* __restrict__ u4, float* __restrict__ oijb)
{
  const int db = blockIdx.x;
  const int d = db >> 2, b = db & 3;
  __shared__ float S[36];
  if (threadIdx.x == 0) {
    const int sidx = (d == 0) ? 1 : 0;
    const int tidx = 1 - sidx;
    float k3[9], sr[9], st[3], tr[9], tt[3];
    const float Wf = 32.0f * 16.0f / 9.0f;
    for (int j = 0; j < 3; ++j) {
      k3[j]     = intr[(b * 4 + 0) * 4 + j] * Wf;
      k3[3 + j] = intr[(b * 4 + 1) * 4 + j] * 32.0f;
      k3[6 + j] = intr[(b * 4 + 2) * 4 + j];
    }
    k3[2] = 16.0f; k3[5] = 16.0f;
    for (int i = 0; i < 3; ++i) {
      for (int j = 0; j < 3; ++j) {
        sr[i * 3 + j] = c2w[((sidx * 4 + b) * 4 + i) * 4 + j];
        tr[i * 3 + j] = c2w[((tidx * 4 + b) * 4 + i) * 4 + j];
      }
      st[i] = c2w[((sidx * 4 + b) * 4 + i) * 4 + 3];
      tt[i] = c2w[((tidx * 4 + b) * 4 + i) * 4 + 3];
    }
    double a = tr[0], bb_ = tr[1], c = tr[2];
    double dd2 = tr[3], e = tr[4], f = tr[5];
    double g2 = tr[6], h2 = tr[7], i2 = tr[8];
    double det = a * (e * i2 - f * h2) - bb_ * (dd2 * i2 - f * g2) + c * (dd2 * h2 - e * g2);
    double inv[9] = {
      (e * i2 - f * h2), (c * h2 - bb_ * i2), (bb_ * f - c * e),
      (f * g2 - dd2 * i2), (a * i2 - c * g2), (c * dd2 - a * f),
      (dd2 * h2 - e * g2), (bb_ * g2 - a * h2), (a * e - bb_ * dd2)
    };
    float tri[9];
    for (int t2 = 0; t2 < 9; ++t2) tri[t2] = (float)(inv[t2] / det);
    float o2[3], oij[3];
    for (int i3 = 0; i3 < 3; ++i3)
      o2[i3] = tri[i3 * 3] * st[0] + tri[i3 * 3 + 1] * st[1] + tri[i3 * 3 + 2] * st[2] - tt[i3];
    for (int i3 = 0; i3 < 3; ++i3)
      oij[i3] = k3[i3 * 3] * o2[0] + k3[i3 * 3 + 1] * o2[1] + k3[i3 * 3 + 2] * o2[2];
    const float ozf = oij[2];
    oij[0] = oij[0] / ozf; oij[1] = oij[1] / ozf; oij[2] = ozf / ozf;
    for (int t2 = 0; t2 < 9; ++t2) { S[t2] = k3[t2]; S[9 + t2] = sr[t2]; S[21 + t2] = tri[t2]; }
    for (int t2 = 0; t2 < 3; ++t2) { S[18 + t2] = st[t2]; S[30 + t2] = tt[t2]; S[33 + t2] = oij[t2]; }
    oijb[db * 4 + 0] = oij[0]; oijb[db * 4 + 1] = oij[1]; oijb[db * 4 + 2] = oij[2];
    oijb[db * 4 + 3] = 0.f;
  }
  __syncthreads();
  for (int n = threadIdx.x; n < 1024; n += blockDim.x) {
    const float ncx = ((float)(n & 31) - S[2]) / S[0];
    const float ncy = ((float)(n >> 5) - S[5]) / S[4];
    const float p0 = S[9]  * ncx + S[10] * ncy + S[11] + S[18];
    const float p1 = S[12] * ncx + S[13] * ncy + S[14] + S[19];
    const float p2 = S[15] * ncx + S[16] * ncy + S[17] + S[20];
    const float q0 = S[21] * p0 + S[22] * p1 + S[23] * p2 - S[30];
    const float q1 = S[24] * p0 + S[25] * p1 + S[26] * p2 - S[31];
    const float q2 = S[27] * p0 + S[28] * p1 + S[29] * p2 - S[32];
    const float w0 = S[0] * q0 + S[1] * q1 + S[2] * q2;
    const float w1 = S[3] * q0 + S[4] * q1 + S[5] * q2;
    const float w2 = S[6] * q0 + S[7] * q1 + S[8] * q2;
    const float pz = w2 + 1e-6f;
    const float ux = w0 / pz - S[33];
    const float uy = w1 / pz - S[34];
    const float uz = w2 / pz - S[35];
    const float vlen = sqrtf(ux * ux + uy * uy + uz * uz);
    f32x4 uo = {ux, uy, uz, vlen};
    *(f32x4*)&u4[((long)db * 1024 + n) * 4] = uo;
  }
}

// -------------------------------------------- epipolar: dw rows (+row where)
__global__ __launch_bounds__(256)
void epi_dw(const float* __restrict__ u4, const float* __restrict__ oijb,
            float* __restrict__ dw)
{
  const int rowid = blockIdx.x;
  const int db = rowid >> 10;
  const f32x4 U = *(const f32x4*)&u4[(long)rowid * 4];
  const float ox = oijb[db * 4 + 0];
  const float oy = oijb[db * 4 + 1];
  const float oz = oijb[db * 4 + 2];
  const int tid = threadIdx.x;
  __shared__ float red[8];
  float vals[4];
  float mx = -1e30f;
  #pragma unroll
  for (int i = 0; i < 4; ++i) {
    const int m = tid + i * 256;
    const float cx = (float)(m & 31) - ox;
    const float cy = (float)(m >> 5) - oy;
    const float cz = 1.0f - oz;
    const float crx = U.y * cz - U.z * cy;
    const float cry = U.z * cx - U.x * cz;
    const float crz = U.x * cy - U.y * cx;
    const float area = sqrtf(crx * crx + cry * cry + crz * crz);
    const float dist = area / U.w;
    const float t = 50.0f * (dist - 0.5f);
    const float dwv = 1.0f - 1.0f / (1.0f + __expf(-t));
    vals[i] = dwv;
    mx = fmaxf(mx, dwv);
  }
  #pragma unroll
  for (int off = 32; off; off >>= 1) mx = fmaxf(mx, __shfl_down(mx, off));
  const int lane = tid & 63, wid = tid >> 6;
  if (!lane) red[wid] = mx;
  __syncthreads();
  if (!tid) red[4] = fmaxf(fmaxf(red[0], red[1]), fmaxf(red[2], red[3]));
  __syncthreads();
  const bool fill1 = red[4] < 0.5f;
  float* out = dw + (long)rowid * 1024;
  #pragma unroll
  for (int i = 0; i < 4; ++i)
    out[tid + i * 256] = fill1 ? 1.0f : vals[i];
}

// --------- wmap: bf16 map for fattn + f32 wm_full output (fused broadcast)
__global__ __launch_bounds__(256)
void epi_wmap(const float* __restrict__ dw, u16* __restrict__ wm,
              float* __restrict__ wm_full)
{
  __shared__ float tb[32][33];
  const int b = blockIdx.z;
  const int q0 = blockIdx.x * 32;
  const int k0 = blockIdx.y * 32;
  const int tid = threadIdx.x;
  const int i = tid >> 3;
  const int j4 = (tid & 7) * 4;
  const float* d1 = dw + ((long)(4 + b) * 1024 + (k0 + i)) * 1024 + q0 + j4;
  #pragma unroll
  for (int jj = 0; jj < 4; ++jj) tb[i][j4 + jj] = d1[jj];
  __syncthreads();
  const float* d0 = dw + ((long)b * 1024 + (q0 + i)) * 1024 + k0 + j4;
  u16x4 pk;
  f32x4 wf;
  #pragma unroll
  for (int jj = 0; jj < 4; ++jj) {
    const float w = d0[jj] * tb[j4 + jj][i];
    wf[jj] = w;
    pk[jj] = f2b(w);
  }
  *(u16x4*)&wm[((long)b * 1024 + q0 + i) * 1024 + k0 + j4] = pk;
  #pragma unroll
  for (int h = 0; h < HEADS; ++h)
    *(f32x4*)&wm_full[((long)(b * HEADS + h) * 1024 + q0 + i) * 1024 + k0 + j4] = wf;
}

// ---------------------------------------------------------------------------
extern "C" void kernel_launch(void* const* d_in, const int* in_sizes, int n_in,
                              void* d_out, int out_size, void* d_ws, size_t ws_size,
                              hipStream_t stream)
{
  (void)in_sizes; (void)n_in; (void)out_size; (void)ws_size;
  const float* x     = (const float*)d_in[0];
  const float* src   = (const float*)d_in[1];
  const float* intr  = (const float*)d_in[2];
  const float* c2w   = (const float*)d_in[3];
  const float* lnq_g = (const float*)d_in[4];
  const float* lnq_b = (const float*)d_in[5];
  const float* Wq    = (const float*)d_in[6];
  const float* bq    = (const float*)d_in[7];
  const float* lnk_g = (const float*)d_in[8];
  const float* lnk_b = (const float*)d_in[9];
  const float* Wk    = (const float*)d_in[10];
  const float* bk    = (const float*)d_in[11];
  const float* lnv_g = (const float*)d_in[12];
  const float* lnv_b = (const float*)d_in[13];
  const float* Wv    = (const float*)d_in[14];
  const float* bv    = (const float*)d_in[15];
  const float* Wp    = (const float*)d_in[16];
  const float* bp    = (const float*)d_in[17];
  const float* pre_g = (const float*)d_in[18];
  const float* pre_b = (const float*)d_in[19];
  const float* W1    = (const float*)d_in[20];
  const float* b1    = (const float*)d_in[21];
  const float* W2    = (const float*)d_in[22];
  const float* b2    = (const float*)d_in[23];
  const float* post_g= (const float*)d_in[24];
  const float* post_b= (const float*)d_in[25];

  char* ws = (char*)d_ws;
  size_t off = 0;
  auto alloc = [&](size_t bytes) -> char* {
    char* p = ws + off;
    off = (off + bytes + 255) & ~(size_t)255;
    return p;
  };
  const size_t SEQD = (size_t)4096 * 768 * 2;   // 6.29 MB slot

  u16* WqT  = (u16*)alloc(768 * 768 * 2);
  u16* WkvT = (u16*)alloc((size_t)1536 * 768 * 2);
  u16* WpT  = (u16*)alloc(768 * 768 * 2);
  u16* W1T  = (u16*)alloc(768 * 1536 * 2);
  u16* W2T  = (u16*)alloc(1536 * 768 * 2);
  float* bqf  = (float*)alloc(768 * 4);
  float* bkvf = (float*)alloc(1536 * 4);
  float* b1f  = (float*)alloc(1536 * 4);
  char* pool = alloc(6 * SEQD);
  float* u4   = (float*)alloc(8 * 1024 * 4 * 4);
  float* oijb = (float*)alloc(8 * 4 * 4);
  u16* wmapb  = (u16*)alloc((size_t)4 * 1024 * 1024 * 2);
  float* dwbuf = (float*)alloc((size_t)8 * 1024 * 1024 * 4);

  u16* S0 = (u16*)pool;                 // norm(x) -> a
  u16* S1 = (u16*)(pool + SEQD);        // norm(src) -> t0
  u16* S2 = (u16*)(pool + 2 * SEQD);    // q -> z_pure
  u16* S3 = (u16*)(pool + 3 * SEQD);    // kv (S3+S4) -> h (S3+S4)
  u16* S5 = (u16*)(pool + 5 * SEQD);    // vT -> t1

  float* out_z  = (float*)d_out;
  float* out_wm = (float*)d_out + (size_t)4 * 1024 * 768;

  // weight prep (fold LN gains + 0.125 into weights, LN biases into biases)
  trans_all<<<dim3(48, 48, 6), 256, 0, stream>>>(
      Wq, Wk, Wv, Wp, W1, W2, lnq_g, lnk_g, lnv_g, pre_g,
      WqT, WkvT, WpT, W1T, W2T);
  biasfold<<<dim3(6, 4), 256, 0, stream>>>(
      Wq, Wk, Wv, W1, bq, bk, bv, b1, lnq_b, lnk_b, lnv_b, pre_b,
      bqf, bkvf, b1f);

  // epipolar weights -> bf16 map + f32 wm_full output
  epi_setup<<<8, 128, 0, stream>>>(intr, c2w, u4, oijb);
  epi_dw<<<8192, 256, 0, stream>>>(u4, oijb, dwbuf);
  epi_wmap<<<dim3(32, 32, 4), 256, 0, stream>>>(dwbuf, wmapb, out_wm);

  // pure norms
  norm_k<true><<<4096, 256, 0, stream>>>(x, S0);
  norm_k<true><<<4096, 256, 0, stream>>>(src, S1);

  // Q + KV projections (one launch, 576 blocks)
  gemm_qkv<<<dim3(32, 6, 3), 256, 0, stream>>>(S0, S1, WqT, WkvT, bqf, bkvf, S2, S3);

  // V -> vT
  v_transpose<<<dim3(16, 48), 256, 0, stream>>>(S3, S5);

  // fused attention -> a (S0; norm(x) dead)
  fattn<<<dim3(16, 48), 256, 0, stream>>>(S2, S3, S5, wmapb, S0);

  // proj: t0 (S1) = a @ Wp + bp
  gemm_one<false, false><<<dim3(32, 6), 256, 0, stream>>>(
      S0, WpT, bp, nullptr, nullptr, nullptr, S1, 768, 768, 768, 768);

  // z_pure (S2) = norm(t0)
  norm_k<false><<<4096, 256, 0, stream>>>(S1, S2);

  // h (S3+S4) = gelu(z_pure @ W1' + b1')
  gemm_one<true, false><<<dim3(32, 12), 256, 0, stream>>>(
      S2, W1T, b1f, nullptr, nullptr, nullptr, S3, 768, 768, 768, 1536);

  // t1 (S5) = (z_pure*pre_g + pre_b) + (h @ W2 + b2)
  gemm_one<false, true><<<dim3(32, 6), 256, 0, stream>>>(
      S3, W2T, b2, S2, pre_g, pre_b, S5, 1536, 1536, 1536, 768);

  // out_z = LN(t1), f32
  ln_final<<<4096, 256, 0, stream>>>(S5, post_g, post_b, out_z);
}